// Round 1
// baseline (536.145 us; speedup 1.0000x reference)
//
#include <hip/hip_runtime.h>
#include <stdint.h>

#define T_TOK 4096
#define H_DIM 1024
#define E_EXP 8
#define DFF_D 4096
#define HROWS 9216   // 8192 + 8*128 worst-case padding

typedef __attribute__((ext_vector_type(4))) float f32x4;
typedef __attribute__((ext_vector_type(8))) __bf16 bf16x8;

static __device__ __forceinline__ unsigned short f2bf(float f) {
  union { float f; unsigned u; } v; v.f = f;
  unsigned r = v.u + 0x7FFFu + ((v.u >> 16) & 1u);
  return (unsigned short)(r >> 16);
}
static __device__ __forceinline__ float bf2f(unsigned short u) {
  union { unsigned u; float f; } v; v.u = ((unsigned)u) << 16; return v.f;
}
static __device__ __forceinline__ void load_lds16(const void* g, void* l) {
  __builtin_amdgcn_global_load_lds(
      (const __attribute__((address_space(1))) unsigned int*)g,
      (__attribute__((address_space(3))) unsigned int*)l, 16, 0, 0);
}

// ---------------- x -> bf16 ----------------
__global__ void cvt_x_kernel(const float* __restrict__ x, unsigned short* __restrict__ xb) {
  const int i = blockIdx.x * 256 + threadIdx.x;          // 8 elems per thread
  const float4* xv = (const float4*)x;
  float4 a = xv[(size_t)i * 2], b = xv[(size_t)i * 2 + 1];
  ushort4 o0, o1;
  o0.x = f2bf(a.x); o0.y = f2bf(a.y); o0.z = f2bf(a.z); o0.w = f2bf(a.w);
  o1.x = f2bf(b.x); o1.y = f2bf(b.y); o1.z = f2bf(b.z); o1.w = f2bf(b.w);
  *(ushort4*)&xb[(size_t)i * 8]     = o0;
  *(ushort4*)&xb[(size_t)i * 8 + 4] = o1;
}

// ---------------- transpose + convert: dst[c][r] = bf16(src[r][c]) ----------------
// src: [R][C] f32 (per expert, blockIdx.z), dst: [C][R] bf16.  Block (32,8), tile 64r x 32c.
__global__ void tr_cvt_kernel(const float* __restrict__ src0, unsigned short* __restrict__ dst0,
                              int R, int C) {
  __shared__ float tile[64][33];
  const size_t eo = (size_t)blockIdx.z * R * C;
  const float* src = src0 + eo;
  unsigned short* dst = dst0 + eo;
  const int r0 = blockIdx.y * 64, c0 = blockIdx.x * 32;
  const int tx = threadIdx.x, ty = threadIdx.y;
#pragma unroll
  for (int i = 0; i < 8; ++i) {
    int r = ty + i * 8;
    tile[r][tx] = src[(size_t)(r0 + r) * C + c0 + tx];
  }
  __syncthreads();
#pragma unroll
  for (int i = 0; i < 4; ++i) {
    int c = ty + i * 8;          // 0..31
    int r = tx * 2;              // 0..62 even
    unsigned short lo = f2bf(tile[r][c]);
    unsigned short hi = f2bf(tile[r + 1][c]);
    unsigned v = (unsigned)lo | ((unsigned)hi << 16);
    *(unsigned*)&dst[(size_t)(c0 + c) * R + r0 + r] = v;
  }
}

// ---------------- gate: logits, softmax, top-2, scatter, aux partials ----------------
__global__ void gate_kernel(const float* __restrict__ x, const float* __restrict__ gw,
                            const float* __restrict__ gb,
                            int* __restrict__ counts,
                            int* __restrict__ entry_token, float* __restrict__ entry_gate,
                            int* __restrict__ ids, int* __restrict__ slots,
                            float* __restrict__ partials) {
  __shared__ float probs_lds[4][8];
  __shared__ int   topi_lds[4][2];
  const int tid = threadIdx.x;
  const int lane = tid & 63, tl = tid >> 6;
  const int token = blockIdx.x * 4 + tl;
  float a[8];
#pragma unroll
  for (int e = 0; e < 8; ++e) a[e] = 0.f;
#pragma unroll
  for (int i = 0; i < 16; ++i) {
    int k = i * 64 + lane;
    float xv = x[(size_t)token * H_DIM + k];
    const float4* g = (const float4*)&gw[(size_t)k * 8];
    float4 g0 = g[0], g1 = g[1];
    a[0] += xv * g0.x; a[1] += xv * g0.y; a[2] += xv * g0.z; a[3] += xv * g0.w;
    a[4] += xv * g1.x; a[5] += xv * g1.y; a[6] += xv * g1.z; a[7] += xv * g1.w;
  }
  for (int m = 32; m >= 1; m >>= 1) {
#pragma unroll
    for (int e = 0; e < 8; ++e) a[e] += __shfl_xor(a[e], m);
  }
  if (lane == 0) {
    float lg[8], p[8];
    float mx = -1e30f;
#pragma unroll
    for (int e = 0; e < 8; ++e) { lg[e] = a[e] + gb[e]; mx = lg[e] > mx ? lg[e] : mx; }
    float s = 0.f;
#pragma unroll
    for (int e = 0; e < 8; ++e) { p[e] = expf(lg[e] - mx); s += p[e]; }
    float inv = 1.f / s;
#pragma unroll
    for (int e = 0; e < 8; ++e) p[e] *= inv;
    int i0 = 0;
#pragma unroll
    for (int e = 1; e < 8; ++e) if (p[e] > p[i0]) i0 = e;
    int i1 = (i0 == 0) ? 1 : 0;
#pragma unroll
    for (int e = 0; e < 8; ++e) if (e != i0 && p[e] > p[i1]) i1 = e;
#pragma unroll
    for (int e = 0; e < 8; ++e) probs_lds[tl][e] = p[e];
    topi_lds[tl][0] = i0; topi_lds[tl][1] = i1;
    int s0 = atomicAdd(&counts[i0], 1);
    entry_token[i0 * T_TOK + s0] = token;
    entry_gate[i0 * T_TOK + s0] = p[i0];
    ids[token * 2] = i0; slots[token * 2] = s0;
    int s1 = atomicAdd(&counts[i1], 1);
    entry_token[i1 * T_TOK + s1] = token;
    entry_gate[i1 * T_TOK + s1] = p[i1];
    ids[token * 2 + 1] = i1; slots[token * 2 + 1] = s1;
  }
  __syncthreads();
  if (tid < 24) {
    int e = tid & 7, which = tid >> 3;
    float s = 0.f;
#pragma unroll
    for (int tt = 0; tt < 4; ++tt) {
      float pv = probs_lds[tt][e];
      bool m = (topi_lds[tt][0] == e) || (topi_lds[tt][1] == e);
      if (which == 0) s += pv;
      else if (which == 1) s += m ? 1.f : 0.f;
      else s += m ? pv : 0.f;
    }
    partials[blockIdx.x * 24 + tid] = s;
  }
}

// ---------------- padded prefix offsets ----------------
__global__ void offsets_kernel(const int* __restrict__ counts, int* __restrict__ hoff) {
  if (threadIdx.x == 0 && blockIdx.x == 0) {
    int o = 0;
    for (int e = 0; e < E_EXP; ++e) { hoff[e] = o; o += ((counts[e] + 127) >> 7) << 7; }
    hoff[E_EXP] = o;
  }
}

// ---------------- aux loss ----------------
__global__ void aux_kernel(const float* __restrict__ partials, float* __restrict__ out_aux) {
  __shared__ float sums[24];
  const int tid = threadIdx.x;
  if (tid < 24) {
    float s = 0.f;
    for (int b = 0; b < 1024; ++b) s += partials[b * 24 + tid];
    sums[tid] = s;
  }
  __syncthreads();
  if (tid == 0) {
    float mean = 0.f;
    for (int e = 0; e < 8; ++e) mean += sums[e];
    mean *= 0.125f;
    float var = 0.f;
    for (int e = 0; e < 8; ++e) { float d = sums[e] - mean; var += d * d; }
    var *= (1.f / 7.f);
    float il = var * (1.f / 64.f);
    float lb = 0.f;
    for (int e = 0; e < 8; ++e) lb += (sums[8 + e] / (float)T_TOK) * (sums[16 + e] / (float)T_TOK);
    lb *= 8.f;
    out_aux[0] = il + lb;
  }
}

// ---------------- GEMM1: h = relu(gather(x) @ w1[e] + b1[e]) ----------------
// 128x128 tile, BK=64, 4 waves, 16x16x32 bf16 MFMA.  B pre-transposed [N][K].
__global__ __launch_bounds__(256) void gemm1_kernel(
    const unsigned short* __restrict__ xb,    // [T][1024]
    const unsigned short* __restrict__ w1t,   // [E][4096][1024]
    const float* __restrict__ b1,             // [E][4096]
    const int* __restrict__ counts, const int* __restrict__ hoff,
    const int* __restrict__ entry_token,
    unsigned short* __restrict__ h)           // [HROWS][4096]
{
  const int e = blockIdx.z, rt = blockIdx.y, ct = blockIdx.x;
  const int cnt = counts[e];
  if (rt * 128 >= cnt) return;
  __shared__ __align__(16) unsigned short As[128 * 64];
  __shared__ __align__(16) unsigned short Bs[128 * 64];
  __shared__ int tok[128];
  const int tid = threadIdx.x;
  const int lane = tid & 63, wv = tid >> 6;
  if (tid < 128) {
    int s = rt * 128 + tid;
    if (s >= cnt) s = cnt - 1;
    tok[tid] = entry_token[e * T_TOK + s];
  }
  __syncthreads();
  const unsigned short* bsrc0 = w1t + (size_t)e * DFF_D * H_DIM + (size_t)ct * 128 * H_DIM;
  const unsigned short* asrc[4]; const unsigned short* bsrc[4];
  unsigned short* alds[4]; unsigned short* blds[4];
#pragma unroll
  for (int i = 0; i < 4; ++i) {
    int c = tid + i * 256;
    asrc[i] = xb + (size_t)tok[c >> 3] * H_DIM + (c & 7) * 8;
    bsrc[i] = bsrc0 + (size_t)(c >> 3) * H_DIM + (c & 7) * 8;
    alds[i] = As + (size_t)(wv * 64 + i * 256) * 8;
    blds[i] = Bs + (size_t)(wv * 64 + i * 256) * 8;
  }
  f32x4 acc[4][4];
#pragma unroll
  for (int mi = 0; mi < 4; ++mi)
#pragma unroll
    for (int ni = 0; ni < 4; ++ni) acc[mi][ni] = (f32x4){0.f, 0.f, 0.f, 0.f};
  const int wm = (wv >> 1) * 64, wn = (wv & 1) * 64;
  for (int kt = 0; kt < 16; ++kt) {
    const int k0 = kt * 64;
#pragma unroll
    for (int i = 0; i < 4; ++i) {
      load_lds16(asrc[i] + k0, alds[i]);
      load_lds16(bsrc[i] + k0, blds[i]);
    }
    __syncthreads();
#pragma unroll
    for (int kk = 0; kk < 2; ++kk) {
      bf16x8 af[4], bfr[4];
#pragma unroll
      for (int mi = 0; mi < 4; ++mi)
        af[mi] = *(const bf16x8*)&As[(wm + mi * 16 + (lane & 15)) * 64 + kk * 32 + (lane >> 4) * 8];
#pragma unroll
      for (int ni = 0; ni < 4; ++ni)
        bfr[ni] = *(const bf16x8*)&Bs[(wn + ni * 16 + (lane & 15)) * 64 + kk * 32 + (lane >> 4) * 8];
#pragma unroll
      for (int mi = 0; mi < 4; ++mi)
#pragma unroll
        for (int ni = 0; ni < 4; ++ni)
          acc[mi][ni] = __builtin_amdgcn_mfma_f32_16x16x32_bf16(af[mi], bfr[ni], acc[mi][ni], 0, 0, 0);
    }
    __syncthreads();
  }
  const int rb = hoff[e] + rt * 128;
#pragma unroll
  for (int mi = 0; mi < 4; ++mi)
#pragma unroll
    for (int ni = 0; ni < 4; ++ni) {
      const int n = ct * 128 + wn + ni * 16 + (lane & 15);
      const float bias = b1[e * DFF_D + n];
#pragma unroll
      for (int q = 0; q < 4; ++q) {
        const int m = wm + mi * 16 + (lane >> 4) * 4 + q;
        float v = acc[mi][ni][q] + bias;
        v = v > 0.f ? v : 0.f;
        h[(size_t)(rb + m) * DFF_D + n] = f2bf(v);
      }
    }
}

// ---------------- GEMM2: y = gate * (h @ w2[e] + b2[e]) ----------------
__global__ __launch_bounds__(256) void gemm2_kernel(
    const unsigned short* __restrict__ h,     // [HROWS][4096]
    const unsigned short* __restrict__ w2t,   // [E][1024][4096]
    const float* __restrict__ b2,             // [E][1024]
    const int* __restrict__ counts, const int* __restrict__ hoff,
    const float* __restrict__ entry_gate,
    unsigned short* __restrict__ y)           // [HROWS][1024]
{
  const int e = blockIdx.z, rt = blockIdx.y, ct = blockIdx.x;
  const int cnt = counts[e];
  if (rt * 128 >= cnt) return;
  __shared__ __align__(16) unsigned short As[128 * 64];
  __shared__ __align__(16) unsigned short Bs[128 * 64];
  const int tid = threadIdx.x;
  const int lane = tid & 63, wv = tid >> 6;
  const int rb = hoff[e] + rt * 128;
  const unsigned short* asrc0 = h + (size_t)rb * DFF_D;
  const unsigned short* bsrc0 = w2t + (size_t)e * H_DIM * DFF_D + (size_t)ct * 128 * DFF_D;
  const unsigned short* asrc[4]; const unsigned short* bsrc[4];
  unsigned short* alds[4]; unsigned short* blds[4];
#pragma unroll
  for (int i = 0; i < 4; ++i) {
    int c = tid + i * 256;
    asrc[i] = asrc0 + (size_t)(c >> 3) * DFF_D + (c & 7) * 8;
    bsrc[i] = bsrc0 + (size_t)(c >> 3) * DFF_D + (c & 7) * 8;
    alds[i] = As + (size_t)(wv * 64 + i * 256) * 8;
    blds[i] = Bs + (size_t)(wv * 64 + i * 256) * 8;
  }
  f32x4 acc[4][4];
#pragma unroll
  for (int mi = 0; mi < 4; ++mi)
#pragma unroll
    for (int ni = 0; ni < 4; ++ni) acc[mi][ni] = (f32x4){0.f, 0.f, 0.f, 0.f};
  const int wm = (wv >> 1) * 64, wn = (wv & 1) * 64;
  for (int kt = 0; kt < 64; ++kt) {
    const int k0 = kt * 64;
#pragma unroll
    for (int i = 0; i < 4; ++i) {
      load_lds16(asrc[i] + k0, alds[i]);
      load_lds16(bsrc[i] + k0, blds[i]);
    }
    __syncthreads();
#pragma unroll
    for (int kk = 0; kk < 2; ++kk) {
      bf16x8 af[4], bfr[4];
#pragma unroll
      for (int mi = 0; mi < 4; ++mi)
        af[mi] = *(const bf16x8*)&As[(wm + mi * 16 + (lane & 15)) * 64 + kk * 32 + (lane >> 4) * 8];
#pragma unroll
      for (int ni = 0; ni < 4; ++ni)
        bfr[ni] = *(const bf16x8*)&Bs[(wn + ni * 16 + (lane & 15)) * 64 + kk * 32 + (lane >> 4) * 8];
#pragma unroll
      for (int mi = 0; mi < 4; ++mi)
#pragma unroll
        for (int ni = 0; ni < 4; ++ni)
          acc[mi][ni] = __builtin_amdgcn_mfma_f32_16x16x32_bf16(af[mi], bfr[ni], acc[mi][ni], 0, 0, 0);
    }
    __syncthreads();
  }
#pragma unroll
  for (int mi = 0; mi < 4; ++mi)
#pragma unroll
    for (int ni = 0; ni < 4; ++ni) {
      const int n = ct * 128 + wn + ni * 16 + (lane & 15);
      const float bias = b2[e * H_DIM + n];
#pragma unroll
      for (int q = 0; q < 4; ++q) {
        const int m = wm + mi * 16 + (lane >> 4) * 4 + q;
        const float gate = entry_gate[e * T_TOK + rt * 128 + m];  // garbage on pad rows: never read
        float v = (acc[mi][ni][q] + bias) * gate;
        y[(size_t)(rb + m) * H_DIM + n] = f2bf(v);
      }
    }
}

// ---------------- combine: out[t] = y[row(t,0)] + y[row(t,1)] ----------------
__global__ void combine_kernel(const unsigned short* __restrict__ y,
                               const int* __restrict__ ids, const int* __restrict__ slots,
                               const int* __restrict__ hoff, float* __restrict__ out) {
  const int t = blockIdx.x, tid = threadIdx.x;
  const int i0 = ids[t * 2], i1 = ids[t * 2 + 1];
  const int r0 = hoff[i0] + slots[t * 2];
  const int r1 = hoff[i1] + slots[t * 2 + 1];
  const int c = tid * 4;
  ushort4 a = *(const ushort4*)&y[(size_t)r0 * H_DIM + c];
  ushort4 b = *(const ushort4*)&y[(size_t)r1 * H_DIM + c];
  float4 o;
  o.x = bf2f(a.x) + bf2f(b.x);
  o.y = bf2f(a.y) + bf2f(b.y);
  o.z = bf2f(a.z) + bf2f(b.z);
  o.w = bf2f(a.w) + bf2f(b.w);
  *(float4*)&out[(size_t)t * H_DIM + c] = o;
}

__global__ void ws_fail_kernel(float* out) {
  if (threadIdx.x == 0 && blockIdx.x == 0) out[0] = -12345.0f;
}

// ---------------- workspace layout (bytes) ----------------
#define XB_OFF    ((size_t)0)                 // 8,388,608
#define W1T_OFF   ((size_t)8388608)           // 67,108,864
#define W2T_OFF   ((size_t)75497472)          // 67,108,864
#define H_OFF     ((size_t)142606336)         // 75,497,472
#define Y_OFF     ((size_t)218103808)         // 18,874,368
#define ET_OFF    ((size_t)236978176)         // 131,072
#define EG_OFF    ((size_t)237109248)         // 131,072
#define IDS_OFF   ((size_t)237240320)         // 32,768
#define SLOT_OFF  ((size_t)237273088)         // 32,768
#define CNT_OFF   ((size_t)237305856)         // 64
#define HOFF_OFF  ((size_t)237305920)         // 64
#define PART_OFF  ((size_t)237305984)         // 98,304
#define WS_NEED   ((size_t)237404288)

extern "C" void kernel_launch(void* const* d_in, const int* in_sizes, int n_in,
                              void* d_out, int out_size, void* d_ws, size_t ws_size,
                              hipStream_t stream) {
  const float* x  = (const float*)d_in[0];
  const float* gw = (const float*)d_in[1];
  const float* gb = (const float*)d_in[2];
  const float* w1 = (const float*)d_in[3];
  const float* b1 = (const float*)d_in[4];
  const float* w2 = (const float*)d_in[5];
  const float* b2 = (const float*)d_in[6];
  float* out = (float*)d_out;
  char* ws = (char*)d_ws;

  if (ws_size < WS_NEED) {  // diagnosable sentinel instead of corruption
    ws_fail_kernel<<<1, 64, 0, stream>>>(out);
    return;
  }

  unsigned short* xb  = (unsigned short*)(ws + XB_OFF);
  unsigned short* w1t = (unsigned short*)(ws + W1T_OFF);
  unsigned short* w2t = (unsigned short*)(ws + W2T_OFF);
  unsigned short* h   = (unsigned short*)(ws + H_OFF);
  unsigned short* yb  = (unsigned short*)(ws + Y_OFF);
  int*   etok  = (int*)(ws + ET_OFF);
  float* egate = (float*)(ws + EG_OFF);
  int*   ids   = (int*)(ws + IDS_OFF);
  int*   slots = (int*)(ws + SLOT_OFF);
  int*   counts= (int*)(ws + CNT_OFF);
  int*   hoff  = (int*)(ws + HOFF_OFF);
  float* parts = (float*)(ws + PART_OFF);

  hipMemsetAsync(counts, 0, 32, stream);

  cvt_x_kernel<<<2048, 256, 0, stream>>>(x, xb);
  tr_cvt_kernel<<<dim3(128, 16, 8), dim3(32, 8), 0, stream>>>(w1, w1t, H_DIM, DFF_D);
  tr_cvt_kernel<<<dim3(32, 64, 8),  dim3(32, 8), 0, stream>>>(w2, w2t, DFF_D, H_DIM);
  gate_kernel<<<1024, 256, 0, stream>>>(x, gw, gb, counts, etok, egate, ids, slots, parts);
  offsets_kernel<<<1, 1, 0, stream>>>(counts, hoff);
  aux_kernel<<<1, 256, 0, stream>>>(parts, out + (size_t)T_TOK * H_DIM);
  gemm1_kernel<<<dim3(32, 32, 8), 256, 0, stream>>>(xb, w1t, b1, counts, hoff, etok, h);
  gemm2_kernel<<<dim3(8, 32, 8), 256, 0, stream>>>(h, w2t, b2, counts, hoff, egate, yb);
  combine_kernel<<<4096, 256, 0, stream>>>(yb, ids, slots, hoff, out);
}